// Round 14
// baseline (3463.367 us; speedup 1.0000x reference)
//
#include <hip/hip_runtime.h>

// ---------------------------------------------------------------------------
// 2-layer GRU, T=512, B=64, I=H=512, fp32 in/out. Persistent cooperative
// kernel, 64 WGs x 512 thr (8 waves), layers wavefront-pipelined.
// Round 14 (= r12 skeleton + K-split waves, minimal diff):
//  - 8 compute waves: wave = (side, kq); side = x/h, kq = K-quarter (128).
//    Each wave computes ALL 3 gates for its disjoint K=128 slice -> LDS
//    A-reads drop 384 -> 128 ds_read_b128 per step (r12 re-read each A
//    fragment 3x, serializing ~1.9us on the LDS pipe).
//  - B stationary: bhi/blo[3][4] (96 VGPR) per wave; acc[3][4] (48 VGPR).
//    __launch_bounds__(512,2) caps at 256 VGPR so 2 waves/SIMD always fit.
//  - part[] = 96 tiles (96 KB) aliases alds[] (r11-proven pattern); extra
//    barrier separates MFMA A-reads from part writes.
//  - everything else verbatim r12: DMA 8 rows/wave, u16 flags, split poll
//    domains, L0 x-prefetch, bf16 fresh-address rings, sc0 sc1 stores,
//    entry acquire fence.
// ---------------------------------------------------------------------------

typedef float f32x4 __attribute__((ext_vector_type(4)));
typedef short s16x8 __attribute__((ext_vector_type(8)));
typedef unsigned u32x2 __attribute__((ext_vector_type(2)));
typedef unsigned u32x4 __attribute__((ext_vector_type(4)));

#define GB_T 512
#define NWG 64
#define NTHR 512
#define SLAB 32768  // ushorts per bf16 slab (64 KB)

// float-word offsets inside ws
#define OFF_FLAGS 0
#define OFF_RING1 1024
#define OFF_RING2 (OFF_RING1 + 513 * (SLAB / 2))

__device__ __forceinline__ void st_coh_u16(unsigned short* p, unsigned v) {
  asm volatile("global_store_short %0, %1, off sc0 sc1" ::"v"(p), "v"(v)
               : "memory");
}
__device__ __forceinline__ void st_coh_u32(unsigned* p, unsigned v) {
  asm volatile("global_store_dword %0, %1, off sc0 sc1" ::"v"(p), "v"(v)
               : "memory");
}
__device__ __forceinline__ void st_coh_u32x2(unsigned* p, u32x2 v) {
  asm volatile("global_store_dwordx2 %0, %1, off sc0 sc1" ::"v"(p), "v"(v)
               : "memory");
}
__device__ __forceinline__ void st_coh_u32x4(unsigned* p, u32x4 v) {
  asm volatile("global_store_dwordx4 %0, %1, off sc0 sc1" ::"v"(p), "v"(v)
               : "memory");
}
#define LDC4U(dst, addr)                                  \
  asm volatile("global_load_dwordx4 %0, %1, off sc0 sc1" \
               : "=v"(dst)                                \
               : "v"(addr))

// async global->LDS DMA, 16 B per lane; LDS dest = uniform base + lane*16
__device__ __forceinline__ void dma16(const void* gsrc, void* ldst) {
  __builtin_amdgcn_global_load_lds(
      (const __attribute__((address_space(1))) unsigned*)gsrc,
      (__attribute__((address_space(3))) unsigned*)ldst, 16, 0, 0);
}

// Poll u16 flags: lanes c0..c1-1 each own one 16-B chunk (8 flags).
__device__ __forceinline__ void poll_flags(const unsigned* fbase, int c0,
                                           int c1, unsigned tgt) {
  const int lane = threadIdx.x & 63;
  const bool mine = (lane >= c0) && (lane < c1);
  const unsigned* fp = fbase + lane * 4;
  for (;;) {
    int ok = 1;
    if (mine) {
      u32x4 f;
      LDC4U(f, fp);
      asm volatile("s_waitcnt vmcnt(0)" ::: "memory");
      ok = ((f.x & 0xFFFFu) >= tgt) & ((f.x >> 16) >= tgt) &
           ((f.y & 0xFFFFu) >= tgt) & ((f.y >> 16) >= tgt) &
           ((f.z & 0xFFFFu) >= tgt) & ((f.z >> 16) >= tgt) &
           ((f.w & 0xFFFFu) >= tgt) & ((f.w >> 16) >= tgt);
    }
    if (__all(ok)) break;
    __builtin_amdgcn_s_sleep(1);
  }
}

__device__ __forceinline__ unsigned rne1(float f) {
  unsigned u = __float_as_uint(f);
  return (u + 0x7FFFu + ((u >> 16) & 1u)) >> 16;
}
__device__ __forceinline__ unsigned pack2(float a, float b) {
  return rne1(a) | (rne1(b) << 16);
}

// fp32 row-major [64][512] slab -> tiled bf16-RNE slab (SLAB ushorts)
// tiled halfword idx = (k>>3)*512 + row*8 + (k&7)   [512 threads]
__device__ __forceinline__ void convert_slab(const float* __restrict__ src,
                                             unsigned short* __restrict__ dst,
                                             int tid) {
  const int row = tid & 63;
  const int kg0 = tid >> 6;  // 0..7
#pragma unroll
  for (int i = 0; i < 8; ++i) {
    const int kg = kg0 + 8 * i;  // 0..63
    const float* s = src + row * 512 + kg * 8;
    f32x4 a = *(const f32x4*)s;
    f32x4 b = *(const f32x4*)(s + 4);
    u32x4 o;
    o.x = pack2(a.x, a.y);
    o.y = pack2(a.z, a.w);
    o.z = pack2(b.x, b.y);
    o.w = pack2(b.z, b.w);
    st_coh_u32x4((unsigned*)(dst + kg * 512 + row * 8), o);
  }
}

__global__ void gru_init(float* __restrict__ ws) {
  if (threadIdx.x < 32)
    st_coh_u32(((unsigned*)(ws + OFF_FLAGS)) + threadIdx.x, 0u);
}

__global__ __launch_bounds__(NTHR, 2) void gru_persist(
    const float* __restrict__ x, const float* __restrict__ h0,
    const float* __restrict__ w_ih, const float* __restrict__ w_hh,
    const float* __restrict__ b_ih, const float* __restrict__ b_hh,
    float* __restrict__ out, float* __restrict__ ws) {
  __shared__ unsigned short alds[2][SLAB];  // 128 KB; part[] aliases it
  float* part = (float*)&alds[0][0];        // 96 tiles x 256 f32 = 96 KB

  const int tid = threadIdx.x;
  const int lane = tid & 63;
  const int wave = __builtin_amdgcn_readfirstlane(tid >> 6);  // 0..7
  const int wg = blockIdx.x;
  const int layer = wg >> 5;      // 0 or 1
  const int j0 = (wg & 31) << 4;  // 16 hidden cols per WG

  unsigned short* flags16 = (unsigned short*)(ws + OFF_FLAGS);
  const unsigned* fbase = (const unsigned*)(ws + OFF_FLAGS);
  unsigned short* ring1 = (unsigned short*)(ws + OFF_RING1);
  unsigned short* ring2 = (unsigned short*)(ws + OFF_RING2);

  // ---- prologue A: x -> tiled bf16 scratch in out[] slabs; h0 -> rings ----
  for (int i = 0; i < 8; ++i) {
    const int t = wg * 8 + i;
    convert_slab(x + (size_t)t * 32768,
                 (unsigned short*)(out + (size_t)t * 32768), tid);
  }
  if (wg == 0) convert_slab(h0, ring1, tid);
  if (wg == 1) convert_slab(h0 + 32768, ring2, tid);

  // ---- prologue B: stationary weights in VGPRs ----------------------------
  // wave = side*4 + kq: side 0 = input-side (w_ih), 1 = hidden (w_hh);
  // kq = K-quarter (128 wide). All 3 gates per wave.
  const int side = wave >> 2;
  const int kq = wave & 3;
  const int l15 = lane & 15, lg = lane >> 4;
  s16x8 bhi[3][4], blo[3][4];
  {
    const float* Wm = (side ? w_hh : w_ih) + (size_t)layer * 1536 * 512;
#pragma unroll
    for (int g = 0; g < 3; ++g)
#pragma unroll
      for (int kc = 0; kc < 4; ++kc) {
        const float* p = Wm + (size_t)(g * 512 + j0 + l15) * 512 + kq * 128 +
                         kc * 32 + lg * 8;
        s16x8 vh, vl;
#pragma unroll
        for (int e = 0; e < 8; ++e) {
          float w = p[e];
          unsigned hb = __float_as_uint(w) & 0xFFFF0000u;
          float resid = w - __uint_as_float(hb);
          vh[e] = (short)(hb >> 16);
          vl[e] = (short)(__float_as_uint(resid) >> 16);
        }
        bhi[g][kc] = vh;
        blo[g][kc] = vl;
      }
  }

  // ---- prologue C: per-thread epilogue state in registers (r12 layout) ----
  const int eb = tid >> 3;        // batch row 0..63
  const int ejp = (tid & 7) * 2;  // col pair 0..14
  const int em = eb >> 4, erow = eb & 15;
  float hprev0 = h0[((size_t)(layer * 64 + eb)) * 512 + j0 + ejp];
  float hprev1 = h0[((size_t)(layer * 64 + eb)) * 512 + j0 + ejp + 1];
  float bx0[3], bx1[3], bhh0[3], bhh1[3];
#pragma unroll
  for (int gg = 0; gg < 3; ++gg) {
    bx0[gg] = b_ih[layer * 1536 + gg * 512 + j0 + ejp];
    bx1[gg] = b_ih[layer * 1536 + gg * 512 + j0 + ejp + 1];
    bhh0[gg] = b_hh[layer * 1536 + gg * 512 + j0 + ejp];
    bhh1[gg] = b_hh[layer * 1536 + gg * 512 + j0 + ejp + 1];
  }

  // Drop stale cache lines (poison / prior replay) before cached DMA reads.
  __builtin_amdgcn_fence(__ATOMIC_ACQUIRE, "agent");

  // ---- prologue barrier (flag value 1) ----
  asm volatile("s_waitcnt vmcnt(0)" ::: "memory");
  __syncthreads();
  if (tid == 0) st_coh_u16(&flags16[wg], 1u);
  poll_flags(fbase, 0, 8, 1u);

  // L0: initial x-DMA for t=0 (x-scratch now globally visible).
  if (layer == 0) {
    const char* sx = (const char*)out;
#pragma unroll
    for (int i = 0; i < 8; ++i) {
      const int r = wave * 8 + i;
      dma16(sx + r * 1024 + lane * 16, (char*)&alds[0][0] + r * 1024);
    }
  }

  for (int s = 0; s <= GB_T; ++s) {
    const int t = layer ? s - 1 : s;
    const bool active = layer ? (s >= 1) : (s < GB_T);
    const unsigned tgt = (unsigned)(s + 1);

    // ---- entry poll (split domains) + DMA (verbatim r12) ----
    if (layer == 0) {
      poll_flags(fbase, 0, 4, tgt);
      if (active) {
        const char* src1 = (const char*)(ring1 + (size_t)t * SLAB);
#pragma unroll
        for (int i = 0; i < 8; ++i) {
          const int r = wave * 8 + i;
          dma16(src1 + r * 1024 + lane * 16, (char*)&alds[1][0] + r * 1024);
        }
      }
    } else {
      poll_flags(fbase, 0, 8, tgt);
      if (active) {
        const char* src0 = (const char*)(ring1 + (size_t)(t + 1) * SLAB);
        const char* src1 = (const char*)(ring2 + (size_t)t * SLAB);
#pragma unroll
        for (int i = 0; i < 8; ++i) {
          const int r = wave * 8 + i;
          dma16(src0 + r * 1024 + lane * 16, (char*)&alds[0][0] + r * 1024);
          dma16(src1 + r * 1024 + lane * 16, (char*)&alds[1][0] + r * 1024);
        }
      }
    }
    asm volatile("s_waitcnt vmcnt(0)" ::: "memory");
    __syncthreads();  // A: LDS slabs ready

    // ---- MFMA phase: disjoint K=128 slice, all 3 gates ----
    f32x4 acc[3][4];
    if (active) {
#pragma unroll
      for (int g = 0; g < 3; ++g)
#pragma unroll
        for (int m = 0; m < 4; ++m) acc[g][m] = (f32x4)(0.f);
      const char* sb = (const char*)&alds[side][0] + lg * 1024 + l15 * 16;
#pragma unroll
      for (int kc = 0; kc < 4; ++kc) {
        const int kcl = kq * 4 + kc;  // 32-k chunk within slab
        s16x8 ah[4];
#pragma unroll
        for (int m = 0; m < 4; ++m)
          ah[m] = *(const s16x8*)(sb + kcl * 4096 + m * 256);
#pragma unroll
        for (int g = 0; g < 3; ++g) {
          const s16x8 bh = bhi[g][kc], bl = blo[g][kc];
#pragma unroll
          for (int m = 0; m < 4; ++m) {
            acc[g][m] = __builtin_amdgcn_mfma_f32_16x16x32_bf16(
                ah[m], bh, acc[g][m], 0, 0, 0);
            acc[g][m] = __builtin_amdgcn_mfma_f32_16x16x32_bf16(
                ah[m], bl, acc[g][m], 0, 0, 0);
          }
        }
      }
    }
    __syncthreads();  // B1: all A-reads done -> part[] may overwrite alds

    if (active) {
#pragma unroll
      for (int g = 0; g < 3; ++g)
#pragma unroll
        for (int m = 0; m < 4; ++m)
#pragma unroll
          for (int r2 = 0; r2 < 4; ++r2)
            part[(wave * 12 + g * 4 + m) * 256 + (lg * 4 + r2) * 16 + l15] =
                acc[g][m][r2];
    }
    __syncthreads();  // B2: part[] complete

    // ---- epilogue: gates + h update + stores (r12 thread mapping) ----
    if (active) {
      float X0[3], H0[3], X1[3], H1[3];
      const int o0 = erow * 16 + ejp;
#pragma unroll
      for (int gg = 0; gg < 3; ++gg) {
        const int tb = (gg * 4 + em) * 256;
        X0[gg] = part[0 * 3072 + tb + o0] + part[1 * 3072 + tb + o0] +
                 part[2 * 3072 + tb + o0] + part[3 * 3072 + tb + o0] +
                 bx0[gg];
        H0[gg] = part[4 * 3072 + tb + o0] + part[5 * 3072 + tb + o0] +
                 part[6 * 3072 + tb + o0] + part[7 * 3072 + tb + o0] +
                 bhh0[gg];
        X1[gg] = part[0 * 3072 + tb + o0 + 1] + part[1 * 3072 + tb + o0 + 1] +
                 part[2 * 3072 + tb + o0 + 1] + part[3 * 3072 + tb + o0 + 1] +
                 bx1[gg];
        H1[gg] = part[4 * 3072 + tb + o0 + 1] + part[5 * 3072 + tb + o0 + 1] +
                 part[6 * 3072 + tb + o0 + 1] + part[7 * 3072 + tb + o0 + 1] +
                 bhh1[gg];
      }
      const float r0 = 1.f / (1.f + __expf(-(X0[0] + H0[0])));
      const float z0 = 1.f / (1.f + __expf(-(X0[1] + H0[1])));
      const float a0 = X0[2] + r0 * H0[2];
      const float n0 = 1.f - 2.f / (1.f + __expf(2.f * a0));
      const float hn0 = (1.f - z0) * n0 + z0 * hprev0;
      const float r1 = 1.f / (1.f + __expf(-(X1[0] + H1[0])));
      const float z1 = 1.f / (1.f + __expf(-(X1[1] + H1[1])));
      const float a1 = X1[2] + r1 * H1[2];
      const float n1 = 1.f - 2.f / (1.f + __expf(2.f * a1));
      const float hn1 = (1.f - z1) * n1 + z1 * hprev1;
      hprev0 = hn0;
      hprev1 = hn1;
      const int j = j0 + ejp;
      unsigned short* rdst = (layer ? ring2 : ring1) + (size_t)(t + 1) * SLAB +
                             (j >> 3) * 512 + eb * 8 + (j & 7);
      st_coh_u32((unsigned*)rdst, pack2(hn0, hn1));
      if (layer) {
        u32x2 fo;
        fo.x = __float_as_uint(hn0);
        fo.y = __float_as_uint(hn1);
        st_coh_u32x2((unsigned*)(out + (size_t)t * 32768 + eb * 512 + j), fo);
      }
    }
    asm volatile("s_waitcnt vmcnt(0)" ::: "memory");
    __syncthreads();  // C: all stores drained, part reads done
    if (tid == 0) st_coh_u16(&flags16[wg], (unsigned)(s + 2));

    // L0: prefetch next x slab into alds[0] (part reads done at C).
    if (layer == 0 && s + 1 < GB_T) {
      const char* sx = (const char*)(out + (size_t)(s + 1) * 32768);
#pragma unroll
      for (int i = 0; i < 8; ++i) {
        const int r = wave * 8 + i;
        dma16(sx + r * 1024 + lane * 16, (char*)&alds[0][0] + r * 1024);
      }
    }
  }
  asm volatile("s_waitcnt vmcnt(0)" ::: "memory");  // drain final stores
}

extern "C" void kernel_launch(void* const* d_in, const int* in_sizes, int n_in,
                              void* d_out, int out_size, void* d_ws,
                              size_t ws_size, hipStream_t stream) {
  const float* x = (const float*)d_in[0];
  const float* h0 = (const float*)d_in[1];
  const float* w_ih = (const float*)d_in[2];
  const float* w_hh = (const float*)d_in[3];
  const float* b_ih = (const float*)d_in[4];
  const float* b_hh = (const float*)d_in[5];
  float* out = (float*)d_out;
  float* ws = (float*)d_ws;

  gru_init<<<1, 64, 0, stream>>>(ws);

  void* args[] = {(void*)&x,    (void*)&h0,   (void*)&w_ih, (void*)&w_hh,
                  (void*)&b_ih, (void*)&b_hh, (void*)&out,  (void*)&ws};
  (void)hipLaunchCooperativeKernel((const void*)gru_persist, dim3(NWG),
                                   dim3(NTHR), args, 0, stream);
}

// Round 16
// 3142.836 us; speedup vs baseline: 1.1020x; 1.1020x over previous
//
#include <hip/hip_runtime.h>

// ---------------------------------------------------------------------------
// 2-layer GRU, T=512, B=64, I=H=512, fp32 in/out. Persistent cooperative
// kernel, 256 WGs x 512 thr (64 active after prologue), layers pipelined.
// Round 16: DATA-AS-FLAG recurrence (no per-step flags/drains/DMA for h).
//  - h stored as fp16 with mantissa LSB forced to 1 (validity tag, <=2^-11
//    rel err). Ring slabs 1..512 zeroed each call in the prologue (zero and
//    0xAA poison both have tag bits clear -> invalid; also kills stale-valid
//    across graph replays). Consumers poll-load slab granules DIRECTLY into
//    MFMA A-registers (sc0 sc1 dwordx4, retry until all tags set): the step
//    chain is ONE L3 round trip + compute, vs r11-14's drain+flag+poll+DMA.
//  - single-term fp16 MFMA (W fp16 in VGPRs, A fp16): half the MFMA count.
//  - x-side (static) stays DMA->LDS behind the one-time prologue barrier.
//  - part[] (96 KB) aliases xlds (64 KB): hazards fenced by barriers B/C/D.
//  - weights/part/epilogue indexing verbatim from r14 (validated).
// ---------------------------------------------------------------------------

typedef float f32x4 __attribute__((ext_vector_type(4)));
typedef short s16x8 __attribute__((ext_vector_type(8)));
typedef _Float16 f16x8 __attribute__((ext_vector_type(8)));
typedef unsigned u32x2 __attribute__((ext_vector_type(2)));
typedef unsigned u32x4 __attribute__((ext_vector_type(4)));

#define GB_T 512
#define NWG 256
#define NTHR 512
#define SLAB 32768        // halfwords per fp16 slab (64 KB)
#define TAG 0x00010001u   // LSB of both packed halves

// float-word offsets inside ws
#define OFF_PF 0          // 256 u16 prologue flags (128 u32)
#define OFF_RING1 1024
#define OFF_RING2 (OFF_RING1 + 513 * (SLAB / 2))
// ws bytes ~= (1024 + 2*513*16384)*4 ~= 67.2 MB (same as r11/r12)

__device__ __forceinline__ void st_l3_u16(unsigned short* p, unsigned v) {
  asm volatile("global_store_short %0, %1, off sc0 sc1" ::"v"(p), "v"(v)
               : "memory");
}
__device__ __forceinline__ void st_l3_u32(unsigned* p, unsigned v) {
  asm volatile("global_store_dword %0, %1, off sc0 sc1" ::"v"(p), "v"(v)
               : "memory");
}
__device__ __forceinline__ void st_l3_u32x2(unsigned* p, u32x2 v) {
  asm volatile("global_store_dwordx2 %0, %1, off sc0 sc1" ::"v"(p), "v"(v)
               : "memory");
}
__device__ __forceinline__ void st_l3_u32x4(unsigned* p, u32x4 v) {
  asm volatile("global_store_dwordx4 %0, %1, off sc0 sc1" ::"v"(p), "v"(v)
               : "memory");
}
#define LD_L3_X4(dst, addr)                               \
  asm volatile("global_load_dwordx4 %0, %1, off sc0 sc1" \
               : "=v"(dst)                                \
               : "v"(addr))

// async global->LDS DMA, 16 B per lane
__device__ __forceinline__ void dma16(const void* gsrc, void* ldst) {
  __builtin_amdgcn_global_load_lds(
      (const __attribute__((address_space(1))) unsigned*)gsrc,
      (__attribute__((address_space(3))) unsigned*)ldst, 16, 0, 0);
}

__device__ __forceinline__ unsigned short h16(float f) {
  return __builtin_bit_cast(unsigned short, (_Float16)f);
}
__device__ __forceinline__ unsigned packh2t(float a, float b) {
  return ((unsigned)h16(a) | ((unsigned)h16(b) << 16)) | TAG;
}

// prologue barrier poll: lanes 0..31 each watch 8 u16 flags (256 total)
__device__ __forceinline__ void poll_pf(const unsigned* fbase, unsigned tgt) {
  const int lane = threadIdx.x & 63;
  const bool mine = lane < 32;
  const unsigned* fp = fbase + lane * 4;
  for (;;) {
    int ok = 1;
    if (mine) {
      u32x4 f;
      LD_L3_X4(f, fp);
      asm volatile("s_waitcnt vmcnt(0)" ::: "memory");
      ok = ((f.x & 0xFFFFu) >= tgt) & ((f.x >> 16) >= tgt) &
           ((f.y & 0xFFFFu) >= tgt) & ((f.y >> 16) >= tgt) &
           ((f.z & 0xFFFFu) >= tgt) & ((f.z >> 16) >= tgt) &
           ((f.w & 0xFFFFu) >= tgt) & ((f.w >> 16) >= tgt);
    }
    if (__all(ok)) break;
    __builtin_amdgcn_s_sleep(1);
  }
}

// poll-load 16 A-granules (16 B each) until every u32 carries the tag
__device__ __forceinline__ void poll_a(const char* slab, int kq, int lg,
                                       int l15, u32x4* q) {
  const char* base = slab + lg * 1024 + l15 * 16;
  for (;;) {
#pragma unroll
    for (int i = 0; i < 16; ++i) {
      const int kcl = kq * 4 + (i >> 2);
      const int m = i & 3;
      LD_L3_X4(q[i], (const unsigned*)(base + kcl * 4096 + m * 256));
    }
    asm volatile("s_waitcnt vmcnt(0)" ::: "memory");
    unsigned v = 0xFFFFFFFFu;
#pragma unroll
    for (int i = 0; i < 16; ++i) v &= q[i].x & q[i].y & q[i].z & q[i].w;
    if (__all((v & TAG) == TAG)) break;
  }
}

// fp32 row-major [64][512] slab -> tiled tagged-fp16 slab
// halfword idx = (k>>3)*512 + row*8 + (k&7)   [512 threads]
__device__ __forceinline__ void convert_slab(const float* __restrict__ src,
                                             unsigned short* __restrict__ dst,
                                             int tid) {
  const int row = tid & 63;
  const int kg0 = tid >> 6;  // 0..7
#pragma unroll
  for (int i = 0; i < 8; ++i) {
    const int kg = kg0 + 8 * i;  // 0..63
    const float* s = src + row * 512 + kg * 8;
    f32x4 a = *(const f32x4*)s;
    f32x4 b = *(const f32x4*)(s + 4);
    u32x4 o;
    o.x = packh2t(a.x, a.y);
    o.y = packh2t(a.z, a.w);
    o.z = packh2t(b.x, b.y);
    o.w = packh2t(b.z, b.w);
    st_l3_u32x4((unsigned*)(dst + kg * 512 + row * 8), o);
  }
}

__global__ void gru_init(float* __restrict__ ws) {
  // zero the prologue-flag region (first 1024 dwords) every call
  unsigned* p = (unsigned*)ws;
  for (int i = threadIdx.x; i < 1024; i += 256) st_l3_u32(&p[i], 0u);
}

__global__ __launch_bounds__(NTHR, 1) void gru_persist(
    const float* __restrict__ x, const float* __restrict__ h0,
    const float* __restrict__ w_ih, const float* __restrict__ w_hh,
    const float* __restrict__ b_ih, const float* __restrict__ b_hh,
    float* __restrict__ out, float* __restrict__ ws) {
  __shared__ float shmem[24576];                  // 96 KB
  unsigned short* xlds = (unsigned short*)shmem;  // first 64 KB (x staging)
  float* part = shmem;                            // 96 tiles x 256 f32

  const int tid = threadIdx.x;
  const int lane = tid & 63;
  const int wave = __builtin_amdgcn_readfirstlane(tid >> 6);  // 0..7
  const int bid = blockIdx.x;
  const int layer = bid >> 5;      // meaningful for bid < 64
  const int j0 = (bid & 31) << 4;  // 16 hidden cols per active WG

  unsigned short* pf = (unsigned short*)(ws + OFF_PF);
  unsigned short* ring1 = (unsigned short*)(ws + OFF_RING1);
  unsigned short* ring2 = (unsigned short*)(ws + OFF_RING2);

  // Drop stale L1/L2 lines (poison / prior replay) before any cached read.
  __builtin_amdgcn_fence(__ATOMIC_ACQUIRE, "agent");
  __syncthreads();

  // ---- prologue 1: zero ring slabs 1..512 of both rings (all 256 WGs) ----
  {
#pragma unroll
    for (int it = 0; it < 32; ++it) {
      const unsigned gidx = ((unsigned)bid * 512u + (unsigned)tid) * 32u + it;
      const unsigned ring = gidx >> 21;       // 512*4096 granules per ring
      const unsigned rem = gidx & 2097151u;
      const unsigned slab = rem >> 12;        // 4096 granules per slab
      const unsigned gg = rem & 4095u;
      unsigned short* base =
          (ring ? ring2 : ring1) + (size_t)(slab + 1) * SLAB + gg * 8;
      u32x4 z = {0u, 0u, 0u, 0u};
      st_l3_u32x4((unsigned*)base, z);
    }
  }

  // ---- prologue 2: x -> tagged fp16 scratch in out[]; h0 -> ring slot 0 --
  for (int i = 0; i < 2; ++i) {
    const int t = bid * 2 + i;
    convert_slab(x + (size_t)t * 32768,
                 (unsigned short*)(out + (size_t)t * 32768), tid);
  }
  if (bid == 0) convert_slab(h0, ring1, tid);
  if (bid == 1) convert_slab(h0 + 32768, ring2, tid);

  // ---- prologue 3 (active WGs): stationary fp16 weights + epilogue state -
  const int side = wave >> 2;
  const int kq = wave & 3;
  const int l15 = lane & 15, lg = lane >> 4;
  f16x8 bw[3][4];
  const int eb = tid >> 3;        // batch row 0..63
  const int ejp = (tid & 7) * 2;  // col pair 0..14
  const int em = eb >> 4, erow = eb & 15;
  float hprev0 = 0.f, hprev1 = 0.f;
  float bx0[3], bx1[3], bhh0[3], bhh1[3];
  if (bid < 64) {
    const float* Wm = (side ? w_hh : w_ih) + (size_t)layer * 1536 * 512;
#pragma unroll
    for (int g = 0; g < 3; ++g)
#pragma unroll
      for (int kc = 0; kc < 4; ++kc) {
        const float* p = Wm + (size_t)(g * 512 + j0 + l15) * 512 + kq * 128 +
                         kc * 32 + lg * 8;
        f16x8 v;
#pragma unroll
        for (int e = 0; e < 8; ++e) v[e] = (_Float16)p[e];
        bw[g][kc] = v;
      }
    hprev0 = h0[((size_t)(layer * 64 + eb)) * 512 + j0 + ejp];
    hprev1 = h0[((size_t)(layer * 64 + eb)) * 512 + j0 + ejp + 1];
#pragma unroll
    for (int gg = 0; gg < 3; ++gg) {
      bx0[gg] = b_ih[layer * 1536 + gg * 512 + j0 + ejp];
      bx1[gg] = b_ih[layer * 1536 + gg * 512 + j0 + ejp + 1];
      bhh0[gg] = b_hh[layer * 1536 + gg * 512 + j0 + ejp];
      bhh1[gg] = b_hh[layer * 1536 + gg * 512 + j0 + ejp + 1];
    }
  }

  // ---- prologue barrier (zeroing + conversions globally visible) ----
  asm volatile("s_waitcnt vmcnt(0)" ::: "memory");
  __syncthreads();
  if (tid == 0) st_l3_u16(&pf[bid], 1u);
  if (bid >= 64) return;  // helpers done
  poll_pf((const unsigned*)pf, 1u);

  // ======================= main loop (flag-free) ==========================
  for (int s = 0; s <= GB_T; ++s) {
    const int t = layer ? s - 1 : s;
    const bool active = layer ? (s >= 1) : (s < GB_T);

    u32x4 q[16];
    if (active) {
      if (layer == 0) {
        if (side == 0) {  // x slab: static, DMA to LDS (waves 0-3, 16 rows)
          const char* sx = (const char*)(out + (size_t)t * 32768);
#pragma unroll
          for (int i = 0; i < 16; ++i) {
            const int r = wave * 16 + i;
            dma16(sx + r * 1024 + lane * 16, (char*)xlds + r * 1024);
          }
        } else {  // h1[t-1]: poll-load to regs
          poll_a((const char*)(ring1 + (size_t)t * SLAB), kq, lg, l15, q);
        }
      } else {
        if (side == 0)  // h1[t]: produced by L0 one step ago (slack ~1 step)
          poll_a((const char*)(ring1 + (size_t)(t + 1) * SLAB), kq, lg, l15, q);
        else  // h2[t-1]: the critical recurrence
          poll_a((const char*)(ring2 + (size_t)t * SLAB), kq, lg, l15, q);
      }
    }
    asm volatile("s_waitcnt vmcnt(0)" ::: "memory");
    __syncthreads();  // A: xlds ready / all A-regs loaded

    // ---- MFMA: disjoint K=128 slice, all 3 gates, single fp16 term ----
    f32x4 acc[3][4];
    if (active) {
#pragma unroll
      for (int g = 0; g < 3; ++g)
#pragma unroll
        for (int m = 0; m < 4; ++m) acc[g][m] = (f32x4)(0.f);
      if (layer == 0 && side == 0) {
        const char* sb = (const char*)xlds + lg * 1024 + l15 * 16;
#pragma unroll
        for (int kc = 0; kc < 4; ++kc) {
          const int kcl = kq * 4 + kc;
          f16x8 ah[4];
#pragma unroll
          for (int m = 0; m < 4; ++m)
            ah[m] = __builtin_bit_cast(
                f16x8, *(const s16x8*)(sb + kcl * 4096 + m * 256));
#pragma unroll
          for (int g = 0; g < 3; ++g) {
            const f16x8 b = bw[g][kc];
#pragma unroll
            for (int m = 0; m < 4; ++m)
              acc[g][m] = __builtin_amdgcn_mfma_f32_16x16x32_f16(
                  ah[m], b, acc[g][m], 0, 0, 0);
          }
        }
      } else {
#pragma unroll
        for (int kc = 0; kc < 4; ++kc) {
#pragma unroll
          for (int g = 0; g < 3; ++g) {
            const f16x8 b = bw[g][kc];
#pragma unroll
            for (int m = 0; m < 4; ++m)
              acc[g][m] = __builtin_amdgcn_mfma_f32_16x16x32_f16(
                  __builtin_bit_cast(f16x8, q[kc * 4 + m]), b, acc[g][m], 0,
                  0, 0);
          }
        }
      }
    }
    __syncthreads();  // B: xlds reads done -> part[] may overwrite

    if (active) {
#pragma unroll
      for (int g = 0; g < 3; ++g)
#pragma unroll
        for (int m = 0; m < 4; ++m)
#pragma unroll
          for (int r2 = 0; r2 < 4; ++r2)
            part[(wave * 12 + g * 4 + m) * 256 + (lg * 4 + r2) * 16 + l15] =
                acc[g][m][r2];
    }
    __syncthreads();  // C: part[] complete

    // ---- epilogue (r14 mapping): gates, h update, tagged store ----
    if (active) {
      float X0[3], H0[3], X1[3], H1[3];
      const int o0 = erow * 16 + ejp;
#pragma unroll
      for (int gg = 0; gg < 3; ++gg) {
        const int tb = (gg * 4 + em) * 256;
        X0[gg] = part[0 * 3072 + tb + o0] + part[1 * 3072 + tb + o0] +
                 part[2 * 3072 + tb + o0] + part[3 * 3072 + tb + o0] +
                 bx0[gg];
        H0[gg] = part[4 * 3072 + tb + o0] + part[5 * 3072 + tb + o0] +
                 part[6 * 3072 + tb + o0] + part[7 * 3072 + tb + o0] +
                 bhh0[gg];
        X1[gg] = part[0 * 3072 + tb + o0 + 1] + part[1 * 3072 + tb + o0 + 1] +
                 part[2 * 3072 + tb + o0 + 1] + part[3 * 3072 + tb + o0 + 1] +
                 bx1[gg];
        H1[gg] = part[4 * 3072 + tb + o0 + 1] + part[5 * 3072 + tb + o0 + 1] +
                 part[6 * 3072 + tb + o0 + 1] + part[7 * 3072 + tb + o0 + 1] +
                 bhh1[gg];
      }
      const float r0 = 1.f / (1.f + __expf(-(X0[0] + H0[0])));
      const float z0 = 1.f / (1.f + __expf(-(X0[1] + H0[1])));
      const float a0 = X0[2] + r0 * H0[2];
      const float n0 = 1.f - 2.f / (1.f + __expf(2.f * a0));
      const float hn0 = (1.f - z0) * n0 + z0 * hprev0;
      const float r1 = 1.f / (1.f + __expf(-(X1[0] + H1[0])));
      const float z1 = 1.f / (1.f + __expf(-(X1[1] + H1[1])));
      const float a1 = X1[2] + r1 * H1[2];
      const float n1 = 1.f - 2.f / (1.f + __expf(2.f * a1));
      const float hn1 = (1.f - z1) * n1 + z1 * hprev1;
      hprev0 = hn0;
      hprev1 = hn1;

      const int j = j0 + ejp;
      const int toff = (j >> 3) * 512 + eb * 8 + (j & 7);
      unsigned short* rdst =
          (layer ? ring2 : ring1) + (size_t)(t + 1) * SLAB + toff;
      st_l3_u32((unsigned*)rdst, packh2t(hn0, hn1));  // fire and forget
      if (layer) {
        u32x2 fo;
        fo.x = __float_as_uint(hn0);
        fo.y = __float_as_uint(hn1);
        st_l3_u32x2((unsigned*)(out + (size_t)t * 32768 + eb * 512 + j), fo);
      }
    }
    __syncthreads();  // D: part reads done -> next step may DMA into xlds
  }
  asm volatile("s_waitcnt vmcnt(0)" ::: "memory");  // drain final stores
}

extern "C" void kernel_launch(void* const* d_in, const int* in_sizes, int n_in,
                              void* d_out, int out_size, void* d_ws,
                              size_t ws_size, hipStream_t stream) {
  const float* x = (const float*)d_in[0];
  const float* h0 = (const float*)d_in[1];
  const float* w_ih = (const float*)d_in[2];
  const float* w_hh = (const float*)d_in[3];
  const float* b_ih = (const float*)d_in[4];
  const float* b_hh = (const float*)d_in[5];
  float* out = (float*)d_out;
  float* ws = (float*)d_ws;

  gru_init<<<1, 256, 0, stream>>>(ws);

  void* args[] = {(void*)&x,    (void*)&h0,   (void*)&w_ih, (void*)&w_hh,
                  (void*)&b_ih, (void*)&b_hh, (void*)&out,  (void*)&ws};
  (void)hipLaunchCooperativeKernel((const void*)gru_persist, dim3(NWG),
                                   dim3(NTHR), args, 0, stream);
}

// Round 17
// 2034.640 us; speedup vs baseline: 1.7022x; 1.5447x over previous
//
#include <hip/hip_runtime.h>

// ---------------------------------------------------------------------------
// 2-layer GRU, T=512, B=64, I=H=512, fp32 in/out. Persistent cooperative
// kernel, 256 WGs x 512 thr. Round 17: 4-STAGE DECOUPLED PIPELINE.
//   G0 (bid 64-95):  gx1[t] = x[t]@W_ih1+b  (static input, free-running)
//   GA (bid  0-31):  h1[t]  = GRU(gx1[t], h1[t-1]@W_hh1+b)   [K=512 critical]
//   GB (bid 96-127): gx2[t] = h1[t]@W_ih2+b (tracks GA)
//   GC (bid 32-63):  h2[t]  = GRU(gx2[t], h2[t-1]@W_hh2+b) -> out
// Sync is pure data-as-flag: h rings = tagged fp16 (LSB of both packed
// halves); gx rings = fp32 with 2-bit generation tag in mantissa LSBs
// (gen=(t>>4)%3+1, never 0 -> zeroed/poisoned slabs invalid), depth 16,
// back-pressure = producer polls paired granule of consumer's h-ring slab
// (t-14) before writing slot t&15. No grid barrier in the main loop; each
// group runs t=0..511 independently. Per WG: 8 waves x K=64, A polled
// directly into MFMA registers, part[] 96 KB LDS, 2 barriers/step.
// ---------------------------------------------------------------------------

typedef float f32x4 __attribute__((ext_vector_type(4)));
typedef short s16x8 __attribute__((ext_vector_type(8)));
typedef _Float16 f16x8 __attribute__((ext_vector_type(8)));
typedef unsigned u32x2 __attribute__((ext_vector_type(2)));
typedef unsigned u32x4 __attribute__((ext_vector_type(4)));

#define GB_T 512
#define NWG 256
#define NTHR 512
#define SLAB 32768  // halfwords per fp16 h-slab (64 KB)
#define TAG 0x00010001u
#define GXSLAB 98304  // floats per gx slab (64*1536)
#define GXDEPTH 16

// float-word offsets inside ws
#define OFF_PF 0  // 256 u16 prologue flags
#define OFF_RING1 1024
#define OFF_RING2 (OFF_RING1 + 513 * (SLAB / 2))
#define OFF_GX1 (OFF_RING2 + 513 * (SLAB / 2))
#define OFF_GX2 (OFF_GX1 + GXDEPTH * GXSLAB)
// total ~= (1024 + 2*513*16384 + 2*16*98304)*4 ~= 80 MB

__device__ __forceinline__ void st_l3_u16(unsigned short* p, unsigned v) {
  asm volatile("global_store_short %0, %1, off sc0 sc1" ::"v"(p), "v"(v)
               : "memory");
}
__device__ __forceinline__ void st_l3_u32(unsigned* p, unsigned v) {
  asm volatile("global_store_dword %0, %1, off sc0 sc1" ::"v"(p), "v"(v)
               : "memory");
}
__device__ __forceinline__ void st_l3_u32x2(unsigned* p, u32x2 v) {
  asm volatile("global_store_dwordx2 %0, %1, off sc0 sc1" ::"v"(p), "v"(v)
               : "memory");
}
__device__ __forceinline__ void st_l3_u32x4(unsigned* p, u32x4 v) {
  asm volatile("global_store_dwordx4 %0, %1, off sc0 sc1" ::"v"(p), "v"(v)
               : "memory");
}
#define LD_L3_X4(dst, addr)                               \
  asm volatile("global_load_dwordx4 %0, %1, off sc0 sc1" \
               : "=v"(dst)                                \
               : "v"(addr))
#define LD_L3_X2(dst, addr)                               \
  asm volatile("global_load_dwordx2 %0, %1, off sc0 sc1" \
               : "=v"(dst)                                \
               : "v"(addr))
#define LD_L3_U32(dst, addr)                             \
  asm volatile("global_load_dword %0, %1, off sc0 sc1" \
               : "=v"(dst)                               \
               : "v"(addr))

__device__ __forceinline__ unsigned short h16(float f) {
  return __builtin_bit_cast(unsigned short, (_Float16)f);
}
__device__ __forceinline__ unsigned packh2t(float a, float b) {
  return ((unsigned)h16(a) | ((unsigned)h16(b) << 16)) | TAG;
}

// prologue barrier poll: lanes 0..31 each watch 8 u16 flags (256 total)
__device__ __forceinline__ void poll_pf(const unsigned* fbase, unsigned tgt) {
  const int lane = threadIdx.x & 63;
  const bool mine = lane < 32;
  const unsigned* fp = fbase + lane * 4;
  for (;;) {
    int ok = 1;
    if (mine) {
      u32x4 f;
      LD_L3_X4(f, fp);
      asm volatile("s_waitcnt vmcnt(0)" ::: "memory");
      ok = ((f.x & 0xFFFFu) >= tgt) & ((f.x >> 16) >= tgt) &
           ((f.y & 0xFFFFu) >= tgt) & ((f.y >> 16) >= tgt) &
           ((f.z & 0xFFFFu) >= tgt) & ((f.z >> 16) >= tgt) &
           ((f.w & 0xFFFFu) >= tgt) & ((f.w >> 16) >= tgt);
    }
    if (__all(ok)) break;
    __builtin_amdgcn_s_sleep(1);
  }
}

// poll-load 8 tagged A-granules (wave's K=64 slice) into MFMA regs
__device__ __forceinline__ void poll_a8(const char* slab, int w, int lg,
                                        int l15, u32x4* q) {
  const char* base = slab + lg * 1024 + l15 * 16;
  for (;;) {
#pragma unroll
    for (int i = 0; i < 8; ++i) {
      const int kcl = w * 2 + (i >> 2);
      const int m = i & 3;
      LD_L3_X4(q[i], (const unsigned*)(base + kcl * 4096 + m * 256));
    }
    asm volatile("s_waitcnt vmcnt(0)" ::: "memory");
    unsigned v = 0xFFFFFFFFu;
#pragma unroll
    for (int i = 0; i < 8; ++i) v &= q[i].x & q[i].y & q[i].z & q[i].w;
    if (__all((v & TAG) == TAG)) break;
  }
}

// plain cached load of 8 A-granules (static x-scratch)
__device__ __forceinline__ void load_a8(const char* slab, int w, int lg,
                                        int l15, u32x4* q) {
  const char* base = slab + lg * 1024 + l15 * 16;
#pragma unroll
  for (int i = 0; i < 8; ++i) {
    const int kcl = w * 2 + (i >> 2);
    const int m = i & 3;
    q[i] = *(const u32x4*)(base + kcl * 4096 + m * 256);
  }
}

// fp32 row-major [64][512] slab -> tiled tagged-fp16 slab
// halfword idx = (k>>3)*512 + row*8 + (k&7)   [512 threads]
__device__ __forceinline__ void convert_slab(const float* __restrict__ src,
                                             unsigned short* __restrict__ dst,
                                             int tid) {
  const int row = tid & 63;
  const int kg0 = tid >> 6;
#pragma unroll
  for (int i = 0; i < 8; ++i) {
    const int kg = kg0 + 8 * i;
    const float* s = src + row * 512 + kg * 8;
    f32x4 a = *(const f32x4*)s;
    f32x4 b = *(const f32x4*)(s + 4);
    u32x4 o;
    o.x = packh2t(a.x, a.y);
    o.y = packh2t(a.z, a.w);
    o.z = packh2t(b.x, b.y);
    o.w = packh2t(b.z, b.w);
    st_l3_u32x4((unsigned*)(dst + kg * 512 + row * 8), o);
  }
}

__global__ void gru_init(float* __restrict__ ws) {
  unsigned* p = (unsigned*)ws;
  for (int i = threadIdx.x; i < 1024; i += 256) st_l3_u32(&p[i], 0u);
}

__global__ __launch_bounds__(NTHR, 1) void gru_persist(
    const float* __restrict__ x, const float* __restrict__ h0,
    const float* __restrict__ w_ih, const float* __restrict__ w_hh,
    const float* __restrict__ b_ih, const float* __restrict__ b_hh,
    float* __restrict__ out, float* __restrict__ ws) {
  __shared__ float part[24576];  // 96 tiles x 256 f32 = 96 KB

  const int tid = threadIdx.x;
  const int lane = tid & 63;
  const int wave = __builtin_amdgcn_readfirstlane(tid >> 6);  // 0..7
  const int bid = blockIdx.x;
  const int grp = bid >> 5;   // 0 GA, 1 GC, 2 G0, 3 GB (bid<128)
  const int rank = bid & 31;
  const int j0 = rank << 4;

  unsigned short* pf = (unsigned short*)(ws + OFF_PF);
  unsigned short* ring1 = (unsigned short*)(ws + OFF_RING1);
  unsigned short* ring2 = (unsigned short*)(ws + OFF_RING2);
  float* gx1 = ws + OFF_GX1;
  float* gx2 = ws + OFF_GX2;

  // Drop stale L1/L2 lines (poison / prior replay) before any cached read.
  __builtin_amdgcn_fence(__ATOMIC_ACQUIRE, "agent");
  __syncthreads();

  // ---- prologue 1: zero h-ring slabs 1..512 + both gx rings --------------
  {
    const unsigned bt = (unsigned)bid * 512u + (unsigned)tid;  // 0..131071
#pragma unroll
    for (int it = 0; it < 32; ++it) {
      const unsigned gidx = bt * 32u + it;
      const unsigned ring = gidx >> 21;
      const unsigned rem = gidx & 2097151u;
      const unsigned slab = rem >> 12;
      const unsigned gg = rem & 4095u;
      unsigned short* base =
          (ring ? ring2 : ring1) + (size_t)(slab + 1) * SLAB + gg * 8;
      u32x4 z = {0u, 0u, 0u, 0u};
      st_l3_u32x4((unsigned*)base, z);
    }
#pragma unroll
    for (int it = 0; it < 6; ++it) {  // 2*16*98304/4 = 786432 = 131072*6
      const unsigned g = bt * 6u + it;
      u32x4 z = {0u, 0u, 0u, 0u};
      st_l3_u32x4((unsigned*)(gx1 + (size_t)g * 4), z);
    }
  }

  // ---- prologue 2: x -> tagged fp16 scratch in out[]; h0 -> ring slot 0 --
  for (int i = 0; i < 2; ++i) {
    const int t = bid * 2 + i;
    convert_slab(x + (size_t)t * 32768,
                 (unsigned short*)(out + (size_t)t * 32768), tid);
  }
  if (bid == 0) convert_slab(h0, ring1, tid);
  if (bid == 1) convert_slab(h0 + 32768, ring2, tid);

  // ---- prologue 3 (active WGs): stationary weights + per-thread state ----
  const int l15 = lane & 15, lg = lane >> 4;
  const int eb = tid >> 3;        // batch row 0..63
  const int ejp = (tid & 7) * 2;  // col pair 0..14
  const int em = eb >> 4, erow = eb & 15;
  f16x8 bw[3][2];
  float hprev0 = 0.f, hprev1 = 0.f;
  float bb0[3], bb1[3];  // recur: b_hh ; producer: b_ih
  if (bid < 128) {
    const float* Wm;
    const float* bias;
    if (grp == 0) { Wm = w_hh;                     bias = b_hh; }
    else if (grp == 1) { Wm = w_hh + 1536 * 512;   bias = b_hh + 1536; }
    else if (grp == 2) { Wm = w_ih;                bias = b_ih; }
    else { Wm = w_ih + (size_t)1536 * 512;         bias = b_ih + 1536; }
#pragma unroll
    for (int g = 0; g < 3; ++g)
#pragma unroll
      for (int kc = 0; kc < 2; ++kc) {
        const float* p = Wm + (size_t)(g * 512 + j0 + l15) * 512 + wave * 64 +
                         kc * 32 + lg * 8;
        f16x8 v;
#pragma unroll
        for (int e = 0; e < 8; ++e) v[e] = (_Float16)p[e];
        bw[g][kc] = v;
      }
#pragma unroll
    for (int gg = 0; gg < 3; ++gg) {
      bb0[gg] = bias[gg * 512 + j0 + ejp];
      bb1[gg] = bias[gg * 512 + j0 + ejp + 1];
    }
    if (grp < 2) {
      hprev0 = h0[((size_t)(grp * 64 + eb)) * 512 + j0 + ejp];
      hprev1 = h0[((size_t)(grp * 64 + eb)) * 512 + j0 + ejp + 1];
    }
  }

  // ---- prologue barrier ----
  asm volatile("s_waitcnt vmcnt(0)" ::: "memory");
  __syncthreads();
  if (tid == 0) st_l3_u16(&pf[bid], 1u);
  if (bid >= 128) return;
  poll_pf((const unsigned*)pf, 1u);

  // group-specific pointers
  unsigned short* ringA = (grp == 1) ? ring2 : ring1;  // A-src (GA,GB:r1 GC:r2)
  unsigned short* ringW = (grp == 0) ? ring1 : ring2;  // h-ring written (recur)
  unsigned short* ringG = (grp == 2) ? ring1 : ring2;  // guard ring (producer)
  float* gxr = (grp == 0) ? gx1 : gx2;                 // gx read (recur)
  float* gxw = (grp == 2) ? gx1 : gx2;                 // gx write (producer)

  // ======================= main loop: t = 0..511 ==========================
  for (int t = 0; t < GB_T; ++t) {
    // ---- A-operand: 8 granules into regs ----
    u32x4 q[8];
    if (grp == 2) {
      load_a8((const char*)(out + (size_t)t * 32768), wave, lg, l15, q);
    } else {
      const unsigned short* sl =
          (grp == 3) ? ringA + (size_t)(t + 1) * SLAB   // h1[t]
                     : ringA + (size_t)t * SLAB;        // h[t-1]
      poll_a8((const char*)sl, wave, lg, l15, q);
    }

    // ---- MFMA: K=64 slice, all 3 gates ----
    f32x4 acc[3][4];
#pragma unroll
    for (int g = 0; g < 3; ++g)
#pragma unroll
      for (int m = 0; m < 4; ++m) acc[g][m] = (f32x4)(0.f);
#pragma unroll
    for (int kc = 0; kc < 2; ++kc)
#pragma unroll
      for (int g = 0; g < 3; ++g) {
        const f16x8 b = bw[g][kc];
#pragma unroll
        for (int m = 0; m < 4; ++m)
          acc[g][m] = __builtin_amdgcn_mfma_f32_16x16x32_f16(
              __builtin_bit_cast(f16x8, q[kc * 4 + m]), b, acc[g][m], 0, 0, 0);
      }
#pragma unroll
    for (int g = 0; g < 3; ++g)
#pragma unroll
      for (int m = 0; m < 4; ++m)
#pragma unroll
        for (int r2 = 0; r2 < 4; ++r2)
          part[(wave * 12 + g * 4 + m) * 256 + (lg * 4 + r2) * 16 + l15] =
              acc[g][m][r2];
    __syncthreads();  // part[] complete

    // ---- epilogue ----
    const int o0 = erow * 16 + ejp;
    float S0[3], S1[3];
#pragma unroll
    for (int gg = 0; gg < 3; ++gg) {
      const int tb = (gg * 4 + em) * 256;
      S0[gg] = part[0 * 3072 + tb + o0] + part[1 * 3072 + tb + o0] +
               part[2 * 3072 + tb + o0] + part[3 * 3072 + tb + o0] +
               part[4 * 3072 + tb + o0] + part[5 * 3072 + tb + o0] +
               part[6 * 3072 + tb + o0] + part[7 * 3072 + tb + o0] + bb0[gg];
      S1[gg] = part[0 * 3072 + tb + o0 + 1] + part[1 * 3072 + tb + o0 + 1] +
               part[2 * 3072 + tb + o0 + 1] + part[3 * 3072 + tb + o0 + 1] +
               part[4 * 3072 + tb + o0 + 1] + part[5 * 3072 + tb + o0 + 1] +
               part[6 * 3072 + tb + o0 + 1] + part[7 * 3072 + tb + o0 + 1] +
               bb1[gg];
    }
    const unsigned gen = ((unsigned)(t >> 4) % 3u) + 1u;
    const int j = j0 + ejp;
    if (grp < 2) {
      // recurrence: poll gx (X side), combine gates, store tagged h
      const float* gb_ = gxr + (size_t)(t & 15) * GXSLAB + eb * 1536 + j;
      u32x2 gxv[3];
      for (;;) {
        LD_L3_X2(gxv[0], (const unsigned*)gb_);
        LD_L3_X2(gxv[1], (const unsigned*)(gb_ + 512));
        LD_L3_X2(gxv[2], (const unsigned*)(gb_ + 1024));
        asm volatile("s_waitcnt vmcnt(0)" ::: "memory");
        int ok = ((gxv[0].x & 3u) == gen) & ((gxv[0].y & 3u) == gen) &
                 ((gxv[1].x & 3u) == gen) & ((gxv[1].y & 3u) == gen) &
                 ((gxv[2].x & 3u) == gen) & ((gxv[2].y & 3u) == gen);
        if (__all(ok)) break;
        __builtin_amdgcn_s_sleep(1);
      }
      const float r0 =
          1.f / (1.f + __expf(-(__uint_as_float(gxv[0].x) + S0[0])));
      const float z0 =
          1.f / (1.f + __expf(-(__uint_as_float(gxv[1].x) + S0[1])));
      const float a0 = __uint_as_float(gxv[2].x) + r0 * S0[2];
      const float n0 = 1.f - 2.f / (1.f + __expf(2.f * a0));
      const float hn0 = (1.f - z0) * n0 + z0 * hprev0;
      const float r1 =
          1.f / (1.f + __expf(-(__uint_as_float(gxv[0].y) + S1[0])));
      const float z1 =
          1.f / (1.f + __expf(-(__uint_as_float(gxv[1].y) + S1[1])));
      const float a1 = __uint_as_float(gxv[2].y) + r1 * S1[2];
      const float n1 = 1.f - 2.f / (1.f + __expf(2.f * a1));
      const float hn1 = (1.f - z1) * n1 + z1 * hprev1;
      hprev0 = hn0;
      hprev1 = hn1;
      const int toff = (j >> 3) * 512 + eb * 8 + (j & 7);
      st_l3_u32((unsigned*)(ringW + (size_t)(t + 1) * SLAB + toff),
                packh2t(hn0, hn1));
      if (grp == 1) {
        u32x2 fo;
        fo.x = __float_as_uint(hn0);
        fo.y = __float_as_uint(hn1);
        *(u32x2*)(out + (size_t)t * 32768 + eb * 512 + j) = fo;
      }
    } else {
      // producer: guard (ring-reuse back-pressure), then gen-tagged gx store
      if (t >= 15) {
        const int toff = (j >> 3) * 512 + eb * 8 + (j & 7);
        const unsigned short* ga =
            ringG + (size_t)(t - 14) * SLAB + toff;
        for (;;) {
          unsigned v;
          LD_L3_U32(v, (const unsigned*)ga);
          asm volatile("s_waitcnt vmcnt(0)" ::: "memory");
          if (__all((v & TAG) == TAG)) break;
          __builtin_amdgcn_s_sleep(1);
        }
      }
      float* gd = gxw + (size_t)(t & 15) * GXSLAB + eb * 1536 + j;
#pragma unroll
      for (int gg = 0; gg < 3; ++gg) {
        u32x2 o;
        o.x = (__float_as_uint(S0[gg]) & ~3u) | gen;
        o.y = (__float_as_uint(S1[gg]) & ~3u) | gen;
        st_l3_u32x2((unsigned*)(gd + gg * 512), o);
      }
    }
    __syncthreads();  // epilogue part-reads done -> next step may overwrite
  }
  asm volatile("s_waitcnt vmcnt(0)" ::: "memory");  // drain final stores
}

extern "C" void kernel_launch(void* const* d_in, const int* in_sizes, int n_in,
                              void* d_out, int out_size, void* d_ws,
                              size_t ws_size, hipStream_t stream) {
  const float* x = (const float*)d_in[0];
  const float* h0 = (const float*)d_in[1];
  const float* w_ih = (const float*)d_in[2];
  const float* w_hh = (const float*)d_in[3];
  const float* b_ih = (const float*)d_in[4];
  const float* b_hh = (const float*)d_in[5];
  float* out = (float*)d_out;
  float* ws = (float*)d_ws;

  gru_init<<<1, 256, 0, stream>>>(ws);

  void* args[] = {(void*)&x,    (void*)&h0,   (void*)&w_ih, (void*)&w_hh,
                  (void*)&b_ih, (void*)&b_hh, (void*)&out,  (void*)&ws};
  (void)hipLaunchCooperativeKernel((const void*)gru_persist, dim3(NWG),
                                   dim3(NTHR), args, 0, stream);
}

// Round 19
// 1873.980 us; speedup vs baseline: 1.8481x; 1.0857x over previous
//
#include <hip/hip_runtime.h>

// ---------------------------------------------------------------------------
// 2-layer GRU, T=512, B=64, I=H=512, fp32 in/out. Persistent cooperative
// kernel, 256 WGs x 512 thr. Round 19 = r17 (passing, 2035us) + issue-early/
// check-late prefetch of the gx poll and the producer guard. NO protocol
// changes (r18's bundled rewrite hung; reverted).
//   G0 (bid 64-95):  gx1[t] = x[t]@W_ih1+b  (static input, free-running)
//   GA (bid  0-31):  h1[t]  = GRU(gx1[t], h1[t-1]@W_hh1+b)
//   GB (bid 96-127): gx2[t] = h1[t]@W_ih2+b
//   GC (bid 32-63):  h2[t]  = GRU(gx2[t], h2[t-1]@W_hh2+b) -> out
// Sync: data-as-flag (tagged fp16 h-rings; gen-tagged fp32 gx rings depth 16;
// producer back-pressure guard on consumer h-ring slab t-14). The gx loads
// and guard load are ISSUED at the top of the step (addresses depend only on
// t); the gen/tag CHECK happens in the epilogue. poll_a8's internal vmcnt(0)
// covers the prefetched loads (recurrence + GB); G0 does one explicit vmcnt.
// Retry loops identical to r17, so worst case == r17.
// ---------------------------------------------------------------------------

typedef float f32x4 __attribute__((ext_vector_type(4)));
typedef short s16x8 __attribute__((ext_vector_type(8)));
typedef _Float16 f16x8 __attribute__((ext_vector_type(8)));
typedef unsigned u32x2 __attribute__((ext_vector_type(2)));
typedef unsigned u32x4 __attribute__((ext_vector_type(4)));

#define GB_T 512
#define NWG 256
#define NTHR 512
#define SLAB 32768  // halfwords per fp16 h-slab (64 KB)
#define TAG 0x00010001u
#define GXSLAB 98304  // floats per gx slab (64*1536)
#define GXDEPTH 16

// float-word offsets inside ws
#define OFF_PF 0  // 256 u16 prologue flags
#define OFF_RING1 1024
#define OFF_RING2 (OFF_RING1 + 513 * (SLAB / 2))
#define OFF_GX1 (OFF_RING2 + 513 * (SLAB / 2))
#define OFF_GX2 (OFF_GX1 + GXDEPTH * GXSLAB)
// total ~= 80 MB

__device__ __forceinline__ void st_l3_u16(unsigned short* p, unsigned v) {
  asm volatile("global_store_short %0, %1, off sc0 sc1" ::"v"(p), "v"(v)
               : "memory");
}
__device__ __forceinline__ void st_l3_u32(unsigned* p, unsigned v) {
  asm volatile("global_store_dword %0, %1, off sc0 sc1" ::"v"(p), "v"(v)
               : "memory");
}
__device__ __forceinline__ void st_l3_u32x2(unsigned* p, u32x2 v) {
  asm volatile("global_store_dwordx2 %0, %1, off sc0 sc1" ::"v"(p), "v"(v)
               : "memory");
}
__device__ __forceinline__ void st_l3_u32x4(unsigned* p, u32x4 v) {
  asm volatile("global_store_dwordx4 %0, %1, off sc0 sc1" ::"v"(p), "v"(v)
               : "memory");
}
#define LD_L3_X4(dst, addr)                               \
  asm volatile("global_load_dwordx4 %0, %1, off sc0 sc1" \
               : "=v"(dst)                                \
               : "v"(addr))
#define LD_L3_X2(dst, addr)                               \
  asm volatile("global_load_dwordx2 %0, %1, off sc0 sc1" \
               : "=v"(dst)                                \
               : "v"(addr))
#define LD_L3_U32(dst, addr)                             \
  asm volatile("global_load_dword %0, %1, off sc0 sc1" \
               : "=v"(dst)                               \
               : "v"(addr))

__device__ __forceinline__ unsigned short h16(float f) {
  return __builtin_bit_cast(unsigned short, (_Float16)f);
}
__device__ __forceinline__ unsigned packh2t(float a, float b) {
  return ((unsigned)h16(a) | ((unsigned)h16(b) << 16)) | TAG;
}

// prologue barrier poll: lanes 0..31 each watch 8 u16 flags (256 total)
__device__ __forceinline__ void poll_pf(const unsigned* fbase, unsigned tgt) {
  const int lane = threadIdx.x & 63;
  const bool mine = lane < 32;
  const unsigned* fp = fbase + lane * 4;
  for (;;) {
    int ok = 1;
    if (mine) {
      u32x4 f;
      LD_L3_X4(f, fp);
      asm volatile("s_waitcnt vmcnt(0)" ::: "memory");
      ok = ((f.x & 0xFFFFu) >= tgt) & ((f.x >> 16) >= tgt) &
           ((f.y & 0xFFFFu) >= tgt) & ((f.y >> 16) >= tgt) &
           ((f.z & 0xFFFFu) >= tgt) & ((f.z >> 16) >= tgt) &
           ((f.w & 0xFFFFu) >= tgt) & ((f.w >> 16) >= tgt);
    }
    if (__all(ok)) break;
    __builtin_amdgcn_s_sleep(1);
  }
}

// poll-load 8 tagged A-granules (wave's K=64 slice) into MFMA regs
__device__ __forceinline__ void poll_a8(const char* slab, int w, int lg,
                                        int l15, u32x4* q) {
  const char* base = slab + lg * 1024 + l15 * 16;
  for (;;) {
#pragma unroll
    for (int i = 0; i < 8; ++i) {
      const int kcl = w * 2 + (i >> 2);
      const int m = i & 3;
      LD_L3_X4(q[i], (const unsigned*)(base + kcl * 4096 + m * 256));
    }
    asm volatile("s_waitcnt vmcnt(0)" ::: "memory");
    unsigned v = 0xFFFFFFFFu;
#pragma unroll
    for (int i = 0; i < 8; ++i) v &= q[i].x & q[i].y & q[i].z & q[i].w;
    if (__all((v & TAG) == TAG)) break;
  }
}

// plain cached load of 8 A-granules (static x-scratch)
__device__ __forceinline__ void load_a8(const char* slab, int w, int lg,
                                        int l15, u32x4* q) {
  const char* base = slab + lg * 1024 + l15 * 16;
#pragma unroll
  for (int i = 0; i < 8; ++i) {
    const int kcl = w * 2 + (i >> 2);
    const int m = i & 3;
    q[i] = *(const u32x4*)(base + kcl * 4096 + m * 256);
  }
}

// fp32 row-major [64][512] slab -> tiled tagged-fp16 slab
// halfword idx = (k>>3)*512 + row*8 + (k&7)   [512 threads]
__device__ __forceinline__ void convert_slab(const float* __restrict__ src,
                                             unsigned short* __restrict__ dst,
                                             int tid) {
  const int row = tid & 63;
  const int kg0 = tid >> 6;
#pragma unroll
  for (int i = 0; i < 8; ++i) {
    const int kg = kg0 + 8 * i;
    const float* s = src + row * 512 + kg * 8;
    f32x4 a = *(const f32x4*)s;
    f32x4 b = *(const f32x4*)(s + 4);
    u32x4 o;
    o.x = packh2t(a.x, a.y);
    o.y = packh2t(a.z, a.w);
    o.z = packh2t(b.x, b.y);
    o.w = packh2t(b.z, b.w);
    st_l3_u32x4((unsigned*)(dst + kg * 512 + row * 8), o);
  }
}

__global__ void gru_init(float* __restrict__ ws) {
  unsigned* p = (unsigned*)ws;
  for (int i = threadIdx.x; i < 1024; i += 256) st_l3_u32(&p[i], 0u);
}

__global__ __launch_bounds__(NTHR, 1) void gru_persist(
    const float* __restrict__ x, const float* __restrict__ h0,
    const float* __restrict__ w_ih, const float* __restrict__ w_hh,
    const float* __restrict__ b_ih, const float* __restrict__ b_hh,
    float* __restrict__ out, float* __restrict__ ws) {
  __shared__ float part[24576];  // 96 tiles x 256 f32 = 96 KB

  const int tid = threadIdx.x;
  const int lane = tid & 63;
  const int wave = __builtin_amdgcn_readfirstlane(tid >> 6);  // 0..7
  const int bid = blockIdx.x;
  const int grp = bid >> 5;  // 0 GA, 1 GC, 2 G0, 3 GB (bid<128)
  const int rank = bid & 31;
  const int j0 = rank << 4;

  unsigned short* pf = (unsigned short*)(ws + OFF_PF);
  unsigned short* ring1 = (unsigned short*)(ws + OFF_RING1);
  unsigned short* ring2 = (unsigned short*)(ws + OFF_RING2);
  float* gx1 = ws + OFF_GX1;
  float* gx2 = ws + OFF_GX2;

  // Drop stale L1/L2 lines (poison / prior replay) before any cached read.
  __builtin_amdgcn_fence(__ATOMIC_ACQUIRE, "agent");
  __syncthreads();

  // ---- prologue 1: zero h-ring slabs 1..512 + both gx rings --------------
  {
    const unsigned bt = (unsigned)bid * 512u + (unsigned)tid;
#pragma unroll
    for (int it = 0; it < 32; ++it) {
      const unsigned gidx = bt * 32u + it;
      const unsigned ring = gidx >> 21;
      const unsigned rem = gidx & 2097151u;
      const unsigned slab = rem >> 12;
      const unsigned gg = rem & 4095u;
      unsigned short* base =
          (ring ? ring2 : ring1) + (size_t)(slab + 1) * SLAB + gg * 8;
      u32x4 z = {0u, 0u, 0u, 0u};
      st_l3_u32x4((unsigned*)base, z);
    }
#pragma unroll
    for (int it = 0; it < 6; ++it) {
      const unsigned g = bt * 6u + it;
      u32x4 z = {0u, 0u, 0u, 0u};
      st_l3_u32x4((unsigned*)(gx1 + (size_t)g * 4), z);
    }
  }

  // ---- prologue 2: x -> tagged fp16 scratch in out[]; h0 -> ring slot 0 --
  for (int i = 0; i < 2; ++i) {
    const int t = bid * 2 + i;
    convert_slab(x + (size_t)t * 32768,
                 (unsigned short*)(out + (size_t)t * 32768), tid);
  }
  if (bid == 0) convert_slab(h0, ring1, tid);
  if (bid == 1) convert_slab(h0 + 32768, ring2, tid);

  // ---- prologue 3 (active WGs): stationary weights + per-thread state ----
  const int l15 = lane & 15, lg = lane >> 4;
  const int eb = tid >> 3;        // batch row 0..63
  const int ejp = (tid & 7) * 2;  // col pair 0..14
  const int em = eb >> 4, erow = eb & 15;
  f16x8 bw[3][2];
  float hprev0 = 0.f, hprev1 = 0.f;
  float bb0[3], bb1[3];  // recur: b_hh ; producer: b_ih
  if (bid < 128) {
    const float* Wm;
    const float* bias;
    if (grp == 0) { Wm = w_hh;                     bias = b_hh; }
    else if (grp == 1) { Wm = w_hh + 1536 * 512;   bias = b_hh + 1536; }
    else if (grp == 2) { Wm = w_ih;                bias = b_ih; }
    else { Wm = w_ih + (size_t)1536 * 512;         bias = b_ih + 1536; }
#pragma unroll
    for (int g = 0; g < 3; ++g)
#pragma unroll
      for (int kc = 0; kc < 2; ++kc) {
        const float* p = Wm + (size_t)(g * 512 + j0 + l15) * 512 + wave * 64 +
                         kc * 32 + lg * 8;
        f16x8 v;
#pragma unroll
        for (int e = 0; e < 8; ++e) v[e] = (_Float16)p[e];
        bw[g][kc] = v;
      }
#pragma unroll
    for (int gg = 0; gg < 3; ++gg) {
      bb0[gg] = bias[gg * 512 + j0 + ejp];
      bb1[gg] = bias[gg * 512 + j0 + ejp + 1];
    }
    if (grp < 2) {
      hprev0 = h0[((size_t)(grp * 64 + eb)) * 512 + j0 + ejp];
      hprev1 = h0[((size_t)(grp * 64 + eb)) * 512 + j0 + ejp + 1];
    }
  }

  // ---- prologue barrier ----
  asm volatile("s_waitcnt vmcnt(0)" ::: "memory");
  __syncthreads();
  if (tid == 0) st_l3_u16(&pf[bid], 1u);
  if (bid >= 128) return;
  poll_pf((const unsigned*)pf, 1u);

  // group-specific pointers
  unsigned short* ringA = (grp == 1) ? ring2 : ring1;  // A-src (GA,GB:r1 GC:r2)
  unsigned short* ringW = (grp == 0) ? ring1 : ring2;  // h-ring written (recur)
  unsigned short* ringG = (grp == 2) ? ring1 : ring2;  // guard ring (producer)
  float* gxr = (grp == 0) ? gx1 : gx2;                 // gx read (recur)
  float* gxw = (grp == 2) ? gx1 : gx2;                 // gx write (producer)

  const int j = j0 + ejp;
  const int toff = (j >> 3) * 512 + eb * 8 + (j & 7);  // halfword idx (even)

  // ======================= main loop: t = 0..511 ==========================
  for (int t = 0; t < GB_T; ++t) {
    const unsigned gen = ((unsigned)(t >> 4) % 3u) + 1u;

    // ---- ISSUE-EARLY: gx loads (recurrence) / guard load (producer) ----
    u32x2 gxv[3];
    unsigned guardv = TAG;
    const float* gb_ = gxr + (size_t)(t & 15) * GXSLAB + eb * 1536 + j;
    const unsigned* ga =
        (const unsigned*)(ringG + (size_t)(t - 14) * SLAB + toff);
    if (grp < 2) {
      LD_L3_X2(gxv[0], (const unsigned*)gb_);
      LD_L3_X2(gxv[1], (const unsigned*)(gb_ + 512));
      LD_L3_X2(gxv[2], (const unsigned*)(gb_ + 1024));
    } else if (t >= 15) {
      LD_L3_U32(guardv, ga);
    }

    // ---- A-operand: 8 granules into regs ----
    u32x4 q[8];
    if (grp == 2) {
      load_a8((const char*)(out + (size_t)t * 32768), wave, lg, l15, q);
    } else {
      const unsigned short* sl =
          (grp == 3) ? ringA + (size_t)(t + 1) * SLAB   // h1[t]
                     : ringA + (size_t)t * SLAB;        // h[t-1]
      poll_a8((const char*)sl, wave, lg, l15, q);  // vmcnt(0) inside covers
    }                                              // the prefetched loads

    // ---- MFMA: K=64 slice, all 3 gates ----
    f32x4 acc[3][4];
#pragma unroll
    for (int g = 0; g < 3; ++g)
#pragma unroll
      for (int m = 0; m < 4; ++m) acc[g][m] = (f32x4)(0.f);
#pragma unroll
    for (int kc = 0; kc < 2; ++kc)
#pragma unroll
      for (int g = 0; g < 3; ++g) {
        const f16x8 b = bw[g][kc];
#pragma unroll
        for (int m = 0; m < 4; ++m)
          acc[g][m] = __builtin_amdgcn_mfma_f32_16x16x32_f16(
              __builtin_bit_cast(f16x8, q[kc * 4 + m]), b, acc[g][m], 0, 0, 0);
      }
#pragma unroll
    for (int g = 0; g < 3; ++g)
#pragma unroll
      for (int m = 0; m < 4; ++m)
#pragma unroll
        for (int r2 = 0; r2 < 4; ++r2)
          part[(wave * 12 + g * 4 + m) * 256 + (lg * 4 + r2) * 16 + l15] =
              acc[g][m][r2];
    __syncthreads();  // part[] complete

    // ---- epilogue ----
    const int o0 = erow * 16 + ejp;
    float S0[3], S1[3];
#pragma unroll
    for (int gg = 0; gg < 3; ++gg) {
      const int tb = (gg * 4 + em) * 256;
      S0[gg] = part[0 * 3072 + tb + o0] + part[1 * 3072 + tb + o0] +
               part[2 * 3072 + tb + o0] + part[3 * 3072 + tb + o0] +
               part[4 * 3072 + tb + o0] + part[5 * 3072 + tb + o0] +
               part[6 * 3072 + tb + o0] + part[7 * 3072 + tb + o0] + bb0[gg];
      S1[gg] = part[0 * 3072 + tb + o0 + 1] + part[1 * 3072 + tb + o0 + 1] +
               part[2 * 3072 + tb + o0 + 1] + part[3 * 3072 + tb + o0 + 1] +
               part[4 * 3072 + tb + o0 + 1] + part[5 * 3072 + tb + o0 + 1] +
               part[6 * 3072 + tb + o0 + 1] + part[7 * 3072 + tb + o0 + 1] +
               bb1[gg];
    }
    if (grp < 2) {
      // CHECK-LATE: gen check on prefetched gxv; retry path identical to r17
      for (;;) {
        int ok = ((gxv[0].x & 3u) == gen) & ((gxv[0].y & 3u) == gen) &
                 ((gxv[1].x & 3u) == gen) & ((gxv[1].y & 3u) == gen) &
                 ((gxv[2].x & 3u) == gen) & ((gxv[2].y & 3u) == gen);
        if (__all(ok)) break;
        __builtin_amdgcn_s_sleep(1);
        LD_L3_X2(gxv[0], (const unsigned*)gb_);
        LD_L3_X2(gxv[1], (const unsigned*)(gb_ + 512));
        LD_L3_X2(gxv[2], (const unsigned*)(gb_ + 1024));
        asm volatile("s_waitcnt vmcnt(0)" ::: "memory");
      }
      const float r0 =
          1.f / (1.f + __expf(-(__uint_as_float(gxv[0].x) + S0[0])));
      const float z0 =
          1.f / (1.f + __expf(-(__uint_as_float(gxv[1].x) + S0[1])));
      const float a0 = __uint_as_float(gxv[2].x) + r0 * S0[2];
      const float n0 = 1.f - 2.f / (1.f + __expf(2.f * a0));
      const float hn0 = (1.f - z0) * n0 + z0 * hprev0;
      const float r1 =
          1.f / (1.f + __expf(-(__uint_as_float(gxv[0].y) + S1[0])));
      const float z1 =
          1.f / (1.f + __expf(-(__uint_as_float(gxv[1].y) + S1[1])));
      const float a1 = __uint_as_float(gxv[2].y) + r1 * S1[2];
      const float n1 = 1.f - 2.f / (1.f + __expf(2.f * a1));
      const float hn1 = (1.f - z1) * n1 + z1 * hprev1;
      hprev0 = hn0;
      hprev1 = hn1;
      st_l3_u32((unsigned*)(ringW + (size_t)(t + 1) * SLAB + toff),
                packh2t(hn0, hn1));
      if (grp == 1) {
        u32x2 fo;
        fo.x = __float_as_uint(hn0);
        fo.y = __float_as_uint(hn1);
        *(u32x2*)(out + (size_t)t * 32768 + eb * 512 + j) = fo;
      }
    } else {
      // CHECK-LATE guard: cover the prefetched load, then verify/retry
      if (t >= 15) {
        asm volatile("s_waitcnt vmcnt(0)" ::: "memory");
        for (;;) {
          if (__all((guardv & TAG) == TAG)) break;
          __builtin_amdgcn_s_sleep(1);
          LD_L3_U32(guardv, ga);
          asm volatile("s_waitcnt vmcnt(0)" ::: "memory");
        }
      }
      float* gd = gxw + (size_t)(t & 15) * GXSLAB + eb * 1536 + j;
#pragma unroll
      for (int gg = 0; gg < 3; ++gg) {
        u32x2 o;
        o.x = (__float_as_uint(S0[gg]) & ~3u) | gen;
        o.y = (__float_as_uint(S1[gg]) & ~3u) | gen;
        st_l3_u32x2((unsigned*)(gd + gg * 512), o);
      }
    }
    __syncthreads();  // epilogue part-reads done -> next step may overwrite
  }
  asm volatile("s_waitcnt vmcnt(0)" ::: "memory");  // drain final stores
}

extern "C" void kernel_launch(void* const* d_in, const int* in_sizes, int n_in,
                              void* d_out, int out_size, void* d_ws,
                              size_t ws_size, hipStream_t stream) {
  const float* x = (const float*)d_in[0];
  const float* h0 = (const float*)d_in[1];
  const float* w_ih = (const float*)d_in[2];
  const float* w_hh = (const float*)d_in[3];
  const float* b_ih = (const float*)d_in[4];
  const float* b_hh = (const float*)d_in[5];
  float* out = (float*)d_out;
  float* ws = (float*)d_ws;

  gru_init<<<1, 256, 0, stream>>>(ws);

  void* args[] = {(void*)&x,    (void*)&h0,   (void*)&w_ih, (void*)&w_hh,
                  (void*)&b_ih, (void*)&b_hh, (void*)&out,  (void*)&ws};
  (void)hipLaunchCooperativeKernel((const void*)gru_persist, dim3(NWG),
                                   dim3(NTHR), args, 0, stream);
}